// Round 4
// baseline (11350.143 us; speedup 1.0000x reference)
//
#include <hip/hip_runtime.h>
#include <math.h>

#define B_ 16
#define T_ 64
#define DETER_ 4096
#define STOCH_ 512
#define UNITS_ 1024
#define EMBED_ 4096
#define FOUT_ 11264

enum { JOB_IMGIN=0, JOB_GATES=1, JOB_PRIOR=2, JOB_OBS=3, JOB_PRIOR_INIT=4 };

struct SP {
  const float* embed; const float* action; const int* is_first;
  const float* wpad_imgin; const float* b_imgin;
  const float* w_ih; const float* w_hh; const float* b_ih; const float* b_hh;
  const float* w_imgout; const float* b_imgout;
  const float* w_obs; const float* b_obs;
  const float* eps_prior; const float* eps_post;
  const float* deter_m_in;    // masked prev deter (read by gates)
  float*       deter_m_out;   // masked new deter for next step
  float*       dnew;          // unmasked new deter (read by post, written by gates)
  float* stoch_m; float* x_img; float* out;
  int t;
};

__device__ __forceinline__ float4 ld4(const float* p){ return *reinterpret_cast<const float4*>(p); }
__device__ __forceinline__ float sigm(float x){ return 1.f/(1.f+expf(-x)); }
__device__ __forceinline__ float dot4(float4 w, float4 x, float a){
  return fmaf(w.x,x.x, fmaf(w.y,x.y, fmaf(w.z,x.z, fmaf(w.w,x.w, a))));
}

// Direct global->LDS DMA, 16B per lane (wave-uniform LDS base, HW adds lane*16).
__device__ __forceinline__ void g2l16(const float* g, float* l) {
  __builtin_amdgcn_global_load_lds(
      (const __attribute__((address_space(1))) unsigned int*)g,
      (__attribute__((address_space(3))) unsigned int*)l, 16, 0, 0);
}

// ======================= pipelined GATES (GRU) =======================
// 512 thr / 8 waves; wave owns unit j = bid*8 + wave (3 gate rows).
// X: 10 chunks of 512 floats x 16 batches (32KB), double-buffered (64KB LDS).
// Raw s_barrier + counted vmcnt(4): stage(c+1) flies during compute(c).
// Lanes 0-31 accumulate batches 0-7, lanes 32-63 batches 8-15.
__global__ __launch_bounds__(512,4) void gates_pipe(SP p) {
  __shared__ float Xs[16384];
  const int bid = blockIdx.x;
  const int tid = threadIdx.x;
  const int wave = tid>>6, lane = tid&63;
  const int half = lane>>5, sl = lane&31;
  const int t = p.t;
  const int j = bid*8 + wave;
  float* buf0 = Xs; float* buf1 = Xs + 8192;

  float ar[8], az[8], anx[8], anh[8];
  #pragma unroll
  for (int b=0;b<8;++b){ ar[b]=0.f; az[b]=0.f; anx[b]=0.f; anh[b]=0.f; }

  auto stage = [&](float* dst, int c) {
    #pragma unroll
    for (int q=0;q<2;++q) {
      const int b = wave*2+q;
      const float* src = (c<2) ? (p.x_img + b*UNITS_ + c*512)
                               : (p.deter_m_in + b*DETER_ + (c-2)*512);
      g2l16(src + lane*4,       dst + b*512);
      g2l16(src + 256 + lane*4, dst + b*512 + 256);
    }
  };

#define GINNER(AN)                                                      \
  _Pragma("unroll")                                                     \
  for (int it=0; it<4; ++it) {                                          \
    const int k0 = it*128 + sl*4;                                       \
    float4 w_r = ld4(wr+k0), w_z = ld4(wz+k0), w_n = ld4(wn+k0);        \
    _Pragma("unroll")                                                   \
    for (int b=0;b<8;++b) {                                             \
      float4 xv = ld4(cur + (half*8+b)*512 + k0);                       \
      ar[b] = dot4(w_r, xv, ar[b]);                                     \
      az[b] = dot4(w_z, xv, az[b]);                                     \
      AN[b] = dot4(w_n, xv, AN[b]);                                     \
    }                                                                   \
  }

  stage(buf0, 0);
  for (int c=0;c<10;++c) {
    float* cur = (c&1)? buf1 : buf0;
    float* nxt = (c&1)? buf0 : buf1;
    __builtin_amdgcn_s_barrier();                 // readers of nxt (chunk c-1) done
    __builtin_amdgcn_sched_barrier(0);
    if (c < 9) {
      stage(nxt, c+1);                            // 4 g2l16 per wave, in flight
      __builtin_amdgcn_sched_barrier(0);
      asm volatile("s_waitcnt vmcnt(4)" ::: "memory");   // stage(c) landed
    } else {
      asm volatile("s_waitcnt vmcnt(0)" ::: "memory");
    }
    __builtin_amdgcn_sched_barrier(0);
    __builtin_amdgcn_s_barrier();                 // all waves' stage(c) landed

    const float *wr, *wz, *wn;
    if (c < 2) {
      const size_t o = (size_t)c*512;
      wr = p.w_ih + (size_t)j*1024 + o;
      wz = p.w_ih + (size_t)(4096+j)*1024 + o;
      wn = p.w_ih + (size_t)(8192+j)*1024 + o;
      GINNER(anx)
    } else {
      const size_t o = (size_t)(c-2)*512;
      wr = p.w_hh + (size_t)j*4096 + o;
      wz = p.w_hh + (size_t)(4096+j)*4096 + o;
      wn = p.w_hh + (size_t)(8192+j)*4096 + o;
      GINNER(anh)
    }
  }
#undef GINNER

  // butterfly reduce within each 32-lane half
  #pragma unroll
  for (int off=1; off<32; off<<=1) {
    #pragma unroll
    for (int b=0;b<8;++b) {
      ar[b]  += __shfl_xor(ar[b],  off);
      az[b]  += __shfl_xor(az[b],  off);
      anx[b] += __shfl_xor(anx[b], off);
      anh[b] += __shfl_xor(anh[b], off);
    }
  }
  // results -> buf0 (last compute used buf1; no barrier needed)
  if (sl==0) {
    #pragma unroll
    for (int b=0;b<8;++b) {
      buf0[(wave*4+0)*16 + half*8 + b] = ar[b];
      buf0[(wave*4+1)*16 + half*8 + b] = az[b];
      buf0[(wave*4+2)*16 + half*8 + b] = anx[b];
      buf0[(wave*4+3)*16 + half*8 + b] = anh[b];
    }
  }
  __syncthreads();

  if (tid < 128) {
    int u = tid&7, b = tid>>3;           // jj fast -> 32B-contiguous stores
    int jj = bid*8 + u;
    const float* res = Xs;
    float rs = res[(u*4+0)*16+b] + p.b_ih[jj]          + p.b_hh[jj];
    float zs = res[(u*4+1)*16+b] + p.b_ih[DETER_+jj]   + p.b_hh[DETER_+jj];
    float ni = res[(u*4+2)*16+b] + p.b_ih[2*DETER_+jj];
    float nh = res[(u*4+3)*16+b] + p.b_hh[2*DETER_+jj];
    float rg = sigm(rs), zg = sigm(zs);
    float ng = tanhf(ni + rg*nh);
    float hp = p.deter_m_in[b*DETER_+jj];          // already masked
    float d  = (1.f-zg)*ng + zg*hp;
    p.dnew[b*DETER_+jj] = d;
    int tn = t+1;
    float mb2 = (tn<T_) ? (p.is_first[b*T_+tn] ? 0.f : 1.f) : 0.f;
    p.deter_m_out[b*DETER_+jj] = d*mb2;            // pre-masked for next step
    size_t ob = ((size_t)(b*T_+t))*FOUT_;
    p.out[ob+1536+jj] = d;
    p.out[ob+7168+jj] = d;
  }
}

// ======================= pipelined PRIOR / OBS =======================
// 256 thr / 4 waves; 8 output rows per block (4 mean + 4 std of units bid*4..+3).
template<int JOB>
__device__ __forceinline__ void pipe_mv(const SP& p, int bid, float* Xs) {
  constexpr int NC = (JOB==JOB_OBS)?16:8;
  const int tid = threadIdx.x;
  const int wave = tid>>6, lane = tid&63;
  const int half = lane>>5, sl = lane&31;
  const int t = p.t;
  float* buf0 = Xs; float* buf1 = Xs + 8192;

  float acc[2][8];
  #pragma unroll
  for (int r=0;r<2;++r)
    #pragma unroll
    for (int b=0;b<8;++b) acc[r][b]=0.f;

  int row0, row1;
  {
    int rl0 = wave*2, rl1 = wave*2+1;
    row0 = (rl0<4)? (bid*4+rl0) : (512 + bid*4 + (rl0-4));
    row1 = (rl1<4)? (bid*4+rl1) : (512 + bid*4 + (rl1-4));
  }

  auto stage = [&](float* dst, int c) {
    #pragma unroll
    for (int q=0;q<4;++q) {
      const int b = wave*4+q;
      const float* src;
      if constexpr (JOB==JOB_PRIOR) src = p.dnew + b*DETER_ + c*512;
      else src = (c<8) ? (p.dnew + b*DETER_ + c*512)
                       : (p.embed + ((size_t)(b*T_+t))*EMBED_ + (c-8)*512);
      g2l16(src + lane*4,       dst + b*512);
      g2l16(src + 256 + lane*4, dst + b*512 + 256);
    }
  };

  stage(buf0, 0);
  for (int c=0;c<NC;++c) {
    float* cur = (c&1)? buf1 : buf0;
    float* nxt = (c&1)? buf0 : buf1;
    __builtin_amdgcn_s_barrier();
    __builtin_amdgcn_sched_barrier(0);
    if (c+1 < NC) {
      stage(nxt, c+1);                            // 8 g2l16 per wave
      __builtin_amdgcn_sched_barrier(0);
      asm volatile("s_waitcnt vmcnt(8)" ::: "memory");
    } else {
      asm volatile("s_waitcnt vmcnt(0)" ::: "memory");
    }
    __builtin_amdgcn_sched_barrier(0);
    __builtin_amdgcn_s_barrier();

    const float *w0, *w1;
    if constexpr (JOB==JOB_PRIOR) {
      w0 = p.w_imgout + (size_t)row0*4096 + (size_t)c*512;
      w1 = p.w_imgout + (size_t)row1*4096 + (size_t)c*512;
    } else {
      w0 = p.w_obs + (size_t)row0*8192 + (size_t)c*512;
      w1 = p.w_obs + (size_t)row1*8192 + (size_t)c*512;
    }
    #pragma unroll
    for (int it=0; it<4; ++it) {
      const int k0 = it*128 + sl*4;
      float4 wa = ld4(w0+k0), wb2 = ld4(w1+k0);
      #pragma unroll
      for (int b=0;b<8;++b) {
        float4 xv = ld4(cur + (half*8+b)*512 + k0);
        acc[0][b] = dot4(wa,  xv, acc[0][b]);
        acc[1][b] = dot4(wb2, xv, acc[1][b]);
      }
    }
  }

  #pragma unroll
  for (int off=1; off<32; off<<=1)
    #pragma unroll
    for (int r=0;r<2;++r)
      #pragma unroll
      for (int b=0;b<8;++b)
        acc[r][b] += __shfl_xor(acc[r][b], off);
  if (sl==0) {
    #pragma unroll
    for (int r=0;r<2;++r)
      #pragma unroll
      for (int b=0;b<8;++b)
        buf0[(wave*2+r)*16 + half*8 + b] = acc[r][b];
  }
  __syncthreads();
  const float* res = Xs;

  if constexpr (JOB==JOB_PRIOR) {
    if (tid < 64) {
      int rl = tid&3, b = tid>>2;
      int jj = bid*4 + rl;
      float mean = res[rl*16+b]     + p.b_imgout[jj];
      float sr   = res[(rl+4)*16+b] + p.b_imgout[512+jj];
      float sd = 2.f*sigm(sr*0.5f) + 0.1f; sd = fmaxf(sd, 1e-4f);
      float ep = p.eps_prior[((size_t)t*B_+b)*STOCH_ + jj];
      size_t ob = ((size_t)(b*T_+t))*FOUT_;
      p.out[ob+5632+jj] = fmaf(sd, ep, mean);
      p.out[ob+6144+jj] = mean;
      p.out[ob+6656+jj] = sd;
    }
  } else {
    if (tid < 64) {
      int rl = tid&3, b = tid>>2;
      int jj = bid*4 + rl;
      float mean = res[rl*16+b]     + p.b_obs[jj];
      float sr   = res[(rl+4)*16+b] + p.b_obs[512+jj];
      float sd = 2.f*sigm(sr*0.5f) + 0.1f; sd = fmaxf(sd, 1e-4f);
      float eo = p.eps_post[((size_t)t*B_+b)*STOCH_ + jj];
      float ost = fmaf(sd, eo, mean);
      size_t ob = ((size_t)(b*T_+t))*FOUT_;
      p.out[ob+0+jj]    = ost;
      p.out[ob+512+jj]  = mean;
      p.out[ob+1024+jj] = sd;
      int tn = t+1;
      float mb2 = (tn<T_) ? (p.is_first[b*T_+tn] ? 0.f : 1.f) : 0.f;
      p.stoch_m[b*STOCH_+jj] = ost*mb2;     // pre-masked carry for next step
    }
  }
}

__global__ __launch_bounds__(256,2) void post_pipe(SP p) {
  __shared__ float Xs[16384];
  if (blockIdx.x < 128) pipe_mv<JOB_PRIOR>(p, blockIdx.x, Xs);
  else                  pipe_mv<JOB_OBS>(p, blockIdx.x - 128, Xs);
}

// ======================= old single-buffer path (IMGIN / PRIOR_INIT) =======================
template<int JOB>
__device__ __forceinline__ void stage_async(const SP& p, float* Xs, int c,
                                            int wave, int lane, int tid, int t) {
  __syncthreads();
  constexpr int SEGS = (JOB==JOB_IMGIN) ? 2 : 4;
  #pragma unroll
  for (int q=0;q<4;++q) {
    const int b = wave*4+q;
    const float* src;
    if constexpr (JOB==JOB_PRIOR_INIT)
      src = p.dnew + b*DETER_ + c*1024;
    else // JOB_IMGIN: lower 512 = pre-masked stoch
      src = p.stoch_m + b*STOCH_;
    float* dst = Xs + b*1024;
    #pragma unroll
    for (int seg=0;seg<SEGS;++seg)
      g2l16(src + seg*256 + lane*4, dst + seg*256);
  }
  if constexpr (JOB==JOB_IMGIN) {
    const int kc = tid*4;
    if (kc >= 512) {
      #pragma unroll
      for (int b=0;b<16;++b) {
        float4 v = make_float4(0.f,0.f,0.f,0.f);
        if (kc == 512) {
          float mb = p.is_first[b*T_+t] ? 0.f : 1.f;
          const float* ap = p.action + (b*T_+t)*2;
          float a0 = ap[0], a1 = ap[1];
          v.x = (a0 / fmaxf(fabsf(a0),1.f))*mb;   // ACTION_CLIP=1
          v.y = (a1 / fmaxf(fabsf(a1),1.f))*mb;
        }
        *reinterpret_cast<float4*>(Xs + b*1024 + kc) = v;
      }
    }
  }
  __syncthreads();   // __syncthreads drains vmcnt -> DMA landed
}

template<int JOB>
__device__ __forceinline__ void mv_body(const SP& p, int bid, float* Xs) {
  constexpr int KTOT = (JOB==JOB_IMGIN)?1024:4096;
  constexpr int CHUNKS = KTOT/1024;
  const int tid = threadIdx.x;
  const int wave = tid>>6, lane = tid&63;
  const int half = lane>>5, sl = lane&31;
  const int t = p.t;

  float acc[2][8];
  #pragma unroll
  for (int r=0;r<2;++r)
    #pragma unroll
    for (int b=0;b<8;++b) acc[r][b]=0.f;

  int rowIdx[2];
  #pragma unroll
  for (int r=0;r<2;++r) rowIdx[r] = bid*8 + wave*2 + r;

  for (int c=0;c<CHUNKS;++c) {
    stage_async<JOB>(p, Xs, c, wave, lane, tid, t);
    const float* w0; const float* w1;
    if constexpr (JOB==JOB_IMGIN) {
      w0 = p.wpad_imgin + (size_t)rowIdx[0]*1024;
      w1 = p.wpad_imgin + (size_t)rowIdx[1]*1024;
    } else {
      w0 = p.w_imgout + (size_t)rowIdx[0]*4096 + (size_t)c*1024;
      w1 = p.w_imgout + (size_t)rowIdx[1]*4096 + (size_t)c*1024;
    }
    #pragma unroll
    for (int it=0; it<8; ++it) {
      const int k0 = it*128 + sl*4;
      float4 wa = ld4(w0 + k0), wb2 = ld4(w1 + k0);
      #pragma unroll
      for (int b=0;b<8;++b) {
        float4 xv = ld4(Xs + (half*8+b)*1024 + k0);
        acc[0][b] = dot4(wa,  xv, acc[0][b]);
        acc[1][b] = dot4(wb2, xv, acc[1][b]);
      }
    }
  }

  #pragma unroll
  for (int off=1; off<32; off<<=1)
    #pragma unroll
    for (int r=0;r<2;++r)
      #pragma unroll
      for (int b=0;b<8;++b)
        acc[r][b] += __shfl_xor(acc[r][b], off);
  __syncthreads();
  if (sl==0) {
    #pragma unroll
    for (int r=0;r<2;++r)
      #pragma unroll
      for (int b=0;b<8;++b)
        Xs[(wave*2+r)*16 + half*8 + b] = acc[r][b];
  }
  __syncthreads();
  const float* res = Xs;

  if constexpr (JOB==JOB_IMGIN) {
    if (tid < 128) {
      int rl = tid&7, b = tid>>3;
      int row = bid*8 + rl;
      p.x_img[b*UNITS_+row] = res[rl*16+b] + p.b_imgin[row];
    }
  } else { // JOB_PRIOR_INIT: stoch0 = mean part, pre-masked with mask(0)
    if (tid < 128) {
      int rl = tid&7, b = tid>>3;
      int row = bid*8 + rl;          // row < 512 (mean rows)
      float mean = res[rl*16+b] + p.b_imgout[row];
      float mb = p.is_first[b*T_+0] ? 0.f : 1.f;
      p.stoch_m[b*STOCH_+row] = mean*mb;
    }
  }
}

template<int JOB>
__global__ __launch_bounds__(256,2) void mv_single(SP p) {
  __shared__ float Xs[16*1024];
  mv_body<JOB>(p, blockIdx.x, Xs);
}

__global__ void pad_imgin_kernel(const float* w, float* wpad) {
  int row = blockIdx.x;
  for (int k=threadIdx.x; k<1024; k+=256)
    wpad[row*1024+k] = (k<514) ? w[row*514+k] : 0.f;
}

// dnew = tanh(initial) broadcast; deter_m(0) = dnew * mask(0)
__global__ void init_deter_kernel(const float* ini, float* det, float* detm,
                                  const int* is_first) {
  int k = blockIdx.x*256 + threadIdx.x;
  float v = tanhf(ini[k]);
  #pragma unroll
  for (int b=0;b<16;++b) {
    det[b*DETER_+k] = v;
    float mb = is_first[b*T_+0] ? 0.f : 1.f;
    detm[b*DETER_+k] = v*mb;
  }
}

extern "C" void kernel_launch(void* const* d_in, const int* in_sizes, int n_in,
                              void* d_out, int out_size, void* d_ws, size_t ws_size,
                              hipStream_t stream) {
  (void)in_sizes; (void)n_in; (void)out_size; (void)ws_size;
  SP p;
  p.embed     = (const float*)d_in[0];
  p.action    = (const float*)d_in[1];
  p.is_first  = (const int*)  d_in[2];
  const float* initial_deter = (const float*)d_in[3];
  p.w_obs     = (const float*)d_in[4];
  p.b_obs     = (const float*)d_in[5];
  const float* w_imgin       = (const float*)d_in[6];
  p.b_imgin   = (const float*)d_in[7];
  p.w_imgout  = (const float*)d_in[8];
  p.b_imgout  = (const float*)d_in[9];
  p.w_ih      = (const float*)d_in[10];
  p.w_hh      = (const float*)d_in[11];
  p.b_ih      = (const float*)d_in[12];
  p.b_hh      = (const float*)d_in[13];
  p.eps_prior = (const float*)d_in[14];
  p.eps_post  = (const float*)d_in[15];
  p.out = (float*)d_out;

  // ws layout (floats): wpad 1M | dnew 64K | deterM0 64K | deterM1 64K | stoch_m 8K | x_img 16K
  float* ws      = (float*)d_ws;
  float* wpad    = ws;
  float* dnew    = wpad    + 1024*1024;
  float* deterM0 = dnew    + 16*DETER_;
  float* deterM1 = deterM0 + 16*DETER_;
  float* stochm  = deterM1 + 16*DETER_;
  float* ximg    = stochm  + 16*STOCH_;
  p.wpad_imgin = wpad;
  p.stoch_m = stochm;
  p.x_img = ximg;

  pad_imgin_kernel<<<1024,256,0,stream>>>(w_imgin, wpad);
  init_deter_kernel<<<DETER_/256,256,0,stream>>>(initial_deter, dnew, deterM0, p.is_first);

  // stoch0 = mean(stats(deter0 @ w_imgout.T + b)) * mask(0)   (dnew == tanh(deter0) here)
  p.t = 0; p.dnew = dnew; p.deter_m_in = deterM0; p.deter_m_out = deterM1;
  mv_single<JOB_PRIOR_INIT><<<64,256,0,stream>>>(p);

  for (int t=0; t<T_; ++t) {
    p.t = t;
    p.deter_m_in  = (t&1) ? deterM1 : deterM0;
    p.deter_m_out = (t&1) ? deterM0 : deterM1;
    p.dnew        = dnew;
    mv_single<JOB_IMGIN><<<128,256,0,stream>>>(p);   // x_img = imgin(concat(stoch_m, a_m))
    gates_pipe<<<512,512,0,stream>>>(p);             // GRU: dbuf + counted-vmcnt pipeline
    post_pipe<<<256,256,0,stream>>>(p);              // prior + obs, same pipeline
  }
}